// Round 14
// baseline (106793.298 us; speedup 1.0000x reference)
//
#include <hip/hip_runtime.h>
#include <hip/hip_bf16.h>

#define Hh 256
#define G4 1024
#define Bsz 256
#define TN 512
#define LDEC 100

// decoder weight-plane element offsets
#define OD0 0
#define ODR 524288
#define ODH 1048576
#define OPJ 1835008
#define OEM 1900544

typedef __attribute__((ext_vector_type(4))) float f32x4;
typedef __attribute__((ext_vector_type(8))) short s16x8;
typedef __attribute__((ext_vector_type(8))) unsigned short u16x8;

__device__ __forceinline__ unsigned short bf_hi(float v) {
  __hip_bfloat16 h = __float2bfloat16(v);
  return *(unsigned short*)&h;
}
__device__ __forceinline__ float bf_f(unsigned short u) {
  unsigned int x = ((unsigned int)u) << 16;
  return *(float*)&x;
}
__device__ __forceinline__ float sigm(float x) { return 1.f / (1.f + expf(-x)); }

// ---------------- fills ----------------
__global__ void k_fill(float* __restrict__ p, int n, float v) {
  int i = blockIdx.x * 256 + threadIdx.x;
  if (i < n) p[i] = v;
}
__global__ void k_zeroi(int* __restrict__ p, int n) {
  int i = threadIdx.x;
  if (i < n) p[i] = 0;
}

// ---------------- split fp32 -> 2-plane bf16 ----------------
__global__ void k_split(const float* __restrict__ src, unsigned short* __restrict__ hi,
                        unsigned short* __restrict__ lo, int n) {
  int i = blockIdx.x * 256 + threadIdx.x;
  if (i < n) {
    float v = src[i];
    unsigned short h = bf_hi(v);
    hi[i] = h;
    lo[i] = bf_hi(v - bf_f(h));
  }
}

// ---------------- split fp32 -> 3-plane bf16 ----------------
__global__ void k_split3(const float* __restrict__ src, unsigned short* __restrict__ p0,
                         unsigned short* __restrict__ p1, unsigned short* __restrict__ p2,
                         int n) {
  int i = blockIdx.x * 256 + threadIdx.x;
  if (i < n) {
    float v = src[i];
    unsigned short a = bf_hi(v);
    float r1 = v - bf_f(a);
    unsigned short b = bf_hi(r1);
    float r2 = r1 - bf_f(b);
    p0[i] = a;
    p1[i] = b;
    p2[i] = bf_hi(r2);
  }
}

// ---------------- xg GEMM with fused A staging (round-6-verified) ----------------
__global__ __launch_bounds__(256) void k_gemm(
    const short* __restrict__ X, const int* __restrict__ text,
    const unsigned short* __restrict__ eh, const unsigned short* __restrict__ el, int l0,
    int K,
    const unsigned short* __restrict__ wh_, const unsigned short* __restrict__ wl_, int wstride,
    const float* __restrict__ bias, float* __restrict__ xg, int s0, int both) {
  int mt = blockIdx.x, nt = blockIdx.y, z = blockIdx.z;
  int slot, dir, w;
  if (both) { slot = z; dir = z & 1; w = z >> 1; }
  else      { slot = z * 2 + 1; dir = 1; w = z; }
  int s = s0 + w;
  int t = dir ? (TN - 1 - s) : s;
  const unsigned short* wh = wh_ + (size_t)dir * wstride;
  const unsigned short* wl = wl_ + (size_t)dir * wstride;
  const float* bp = bias + dir * G4;
  __shared__ unsigned short Ah[64][40], Al[64][40], Bh[128][40], Bl[128][40];
  int tid = threadIdx.x, wave = tid >> 6, lane = tid & 63;
  f32x4 acc[8];
#pragma unroll
  for (int i = 0; i < 8; ++i) acc[i] = (f32x4){0.f, 0.f, 0.f, 0.f};

  int ar = tid >> 2, akq = (tid & 3) * 8;
  int brow = mt * 64 + ar;
  const unsigned short *aeh = nullptr, *ael = nullptr;
  const short* ax = nullptr;
  if (l0) {
    int tok = text[brow * TN + t];
    aeh = eh + tok * 256 + akq;
    ael = el + tok * 256 + akq;
  } else {
    ax = X + ((size_t)brow * TN + t) * 512 + akq;
  }
  int br = tid >> 1, bkq = (tid & 1) * 16;
  int g = nt * 128 + br;
  const unsigned short* bsrch = wh + (size_t)g * K + bkq;
  const unsigned short* bsrcl = wl + (size_t)g * K + bkq;

  for (int kk = 0; kk < K; kk += 32) {
    __syncthreads();
    if (l0) {
      *(u16x8*)&Ah[ar][akq] = *(const u16x8*)(aeh + kk);
      *(u16x8*)&Al[ar][akq] = *(const u16x8*)(ael + kk);
    } else {
      s16x8 sv = *(const s16x8*)(ax + kk);
      u16x8 hv, lv;
#pragma unroll
      for (int j = 0; j < 8; ++j) {
        float a = (float)sv[j] * (1.f / 32767.f);
        unsigned short h = bf_hi(a);
        hv[j] = h;
        lv[j] = bf_hi(a - bf_f(h));
      }
      *(u16x8*)&Ah[ar][akq] = hv;
      *(u16x8*)&Al[ar][akq] = lv;
    }
    *(u16x8*)&Bh[br][bkq]      = *(const u16x8*)(bsrch + kk);
    *(u16x8*)&Bh[br][bkq + 8]  = *(const u16x8*)(bsrch + kk + 8);
    *(u16x8*)&Bl[br][bkq]      = *(const u16x8*)(bsrcl + kk);
    *(u16x8*)&Bl[br][bkq + 8]  = *(const u16x8*)(bsrcl + kk + 8);
    __syncthreads();

    int m = wave * 16 + (lane & 15);
    int kq = (lane >> 4) * 8;
    s16x8 ah = *(s16x8*)&Ah[m][kq];
    s16x8 al = *(s16x8*)&Al[m][kq];
#pragma unroll
    for (int nf = 0; nf < 8; ++nf) {
      s16x8 bh = *(s16x8*)&Bh[nf * 16 + (lane & 15)][kq];
      s16x8 bl = *(s16x8*)&Bl[nf * 16 + (lane & 15)][kq];
      acc[nf] = __builtin_amdgcn_mfma_f32_16x16x32_bf16(ah, bh, acc[nf], 0, 0, 0);
      acc[nf] = __builtin_amdgcn_mfma_f32_16x16x32_bf16(al, bh, acc[nf], 0, 0, 0);
      acc[nf] = __builtin_amdgcn_mfma_f32_16x16x32_bf16(ah, bl, acc[nf], 0, 0, 0);
    }
  }
  int col = lane & 15, rq = (lane >> 4) * 4;
  float* outp = xg + (size_t)slot * 262144;
#pragma unroll
  for (int nf = 0; nf < 8; ++nf) {
    int gg = nt * 128 + nf * 16 + col;
    float bv = bp[gg];
#pragma unroll
    for (int r = 0; r < 4; ++r) {
      int b = mt * 64 + wave * 16 + rq + r;
      outp[(size_t)b * 1024 + gg] = acc[nf][r] + bv;
    }
  }
}

// 6-product accumulation macro (streamed-B) — ascending magnitude
#define MF6(ACC, P0, P1, P2, WO)                                                         \
  {                                                                                      \
    s16x8 bf0 = *(const s16x8*)&(P0)[WO];                                                \
    s16x8 bf1 = *(const s16x8*)&(P1)[WO];                                                \
    s16x8 bf2 = *(const s16x8*)&(P2)[WO];                                                \
    ACC = __builtin_amdgcn_mfma_f32_16x16x32_bf16(a1, bf1, ACC, 0, 0, 0);                \
    ACC = __builtin_amdgcn_mfma_f32_16x16x32_bf16(a0, bf2, ACC, 0, 0, 0);                \
    ACC = __builtin_amdgcn_mfma_f32_16x16x32_bf16(a2, bf0, ACC, 0, 0, 0);                \
    ACC = __builtin_amdgcn_mfma_f32_16x16x32_bf16(a1, bf0, ACC, 0, 0, 0);                \
    ACC = __builtin_amdgcn_mfma_f32_16x16x32_bf16(a0, bf1, ACC, 0, 0, 0);                \
    ACC = __builtin_amdgcn_mfma_f32_16x16x32_bf16(a0, bf0, ACC, 0, 0, 0);                \
  }

#define MFMA_BF16 __builtin_amdgcn_mfma_f32_16x16x32_bf16

// ---------------- window recurrence (round-11-identical) ----------------
__global__ __launch_bounds__(512) void k_wstep(
    const float* __restrict__ xg,
    const unsigned short* __restrict__ w0, const unsigned short* __restrict__ w1,
    const unsigned short* __restrict__ w2,
    unsigned short* __restrict__ Hg,   // [dir][par][plane][256][256] ushort
    float* __restrict__ Cst,
    short* __restrict__ X, short* __restrict__ Sf, short* __restrict__ Sr,
    float* __restrict__ dec_in, int* __restrict__ bar, int s0, int W, int mode) {
  int jt = blockIdx.x, bs = blockIdx.y, dir = blockIdx.z;
  if (mode == 2 && dir == 0 && s0 != 0) return;
  int nsteps = (mode == 2 && dir == 0) ? 1 : W;
  int j16 = jt * 16;
  int b0 = bs * 128;
  const unsigned short* wp0 = w0 + dir * 262144;
  const unsigned short* wp1 = w1 + dir * 262144;
  const unsigned short* wp2 = w2 + dir * 262144;
  int* cnt = bar + (dir * 2 + bs) * 32;

  __shared__ unsigned short Wl[3][4][16][256];
  int tid = threadIdx.x, lane = tid & 63, wv = tid >> 6;
  int m15 = lane & 15, lq = lane >> 4, hk8 = lq * 8, r0 = lq * 4;

  for (int v = tid; v < 6144; v += 512) {
    int pl = v / 2048;
    int rem = v - pl * 2048;
    int gq = rem >> 9;
    int r = (rem >> 5) & 15;
    int c = rem & 31;
    const unsigned short* wp = (pl == 0) ? wp0 : ((pl == 1) ? wp1 : wp2);
    *(u16x8*)&Wl[pl][gq][r][(c ^ (r & 7)) * 8] =
        *(const u16x8*)&wp[((size_t)(gq * 256 + j16 + r)) * 256 + c * 8];
  }
  f32x4 cx;
  if (s0 == 0) {
    cx = (f32x4){0.f, 0.f, 0.f, 0.f};
  } else {
#pragma unroll
    for (int r = 0; r < 4; ++r)
      cx[r] = Cst[(size_t)dir * 65536 + (b0 + wv * 16 + r0 + r) * 256 + j16 + m15];
  }
  __syncthreads();

  int j = j16 + m15;
  for (int w = 0; w < nsteps; ++w) {
    int s = s0 + w;
    int p0 = s & 1, p1 = p0 ^ 1;
    const float* xgp = xg + (size_t)(2 * w + dir) * 262144;
    const unsigned short* hr0 = Hg + ((size_t)(dir * 2 + p0) * 3 + 0) * 65536;
    const unsigned short* hr1 = Hg + ((size_t)(dir * 2 + p0) * 3 + 1) * 65536;
    const unsigned short* hr2 = Hg + ((size_t)(dir * 2 + p0) * 3 + 2) * 65536;
    unsigned short* hw0 = Hg + ((size_t)(dir * 2 + p1) * 3 + 0) * 65536;
    unsigned short* hw1 = Hg + ((size_t)(dir * 2 + p1) * 3 + 1) * 65536;
    unsigned short* hw2 = Hg + ((size_t)(dir * 2 + p1) * 3 + 2) * 65536;

    float xv[4][4];
#pragma unroll
    for (int r = 0; r < 4; ++r) {
      const float* xr = xgp + (size_t)(b0 + wv * 16 + r0 + r) * 1024 + j;
      xv[r][0] = xr[0];
      xv[r][1] = xr[256];
      xv[r][2] = xr[512];
      xv[r][3] = xr[768];
    }

    f32x4 acc[4];
#pragma unroll
    for (int gq = 0; gq < 4; ++gq) acc[gq] = (f32x4){0.f, 0.f, 0.f, 0.f};

    size_t hbase = (size_t)(b0 + wv * 16 + m15) * 256 + hk8;
    s16x8 a0 = *(const s16x8*)&hr0[hbase];
    s16x8 a1 = *(const s16x8*)&hr1[hbase];
    s16x8 a2 = *(const s16x8*)&hr2[hbase];
#pragma unroll
    for (int kk = 0; kk < 8; ++kk) {
      s16x8 n0, n1, n2;
      if (kk < 7) {
        n0 = *(const s16x8*)&hr0[hbase + (kk + 1) * 32];
        n1 = *(const s16x8*)&hr1[hbase + (kk + 1) * 32];
        n2 = *(const s16x8*)&hr2[hbase + (kk + 1) * 32];
      }
      int cc = ((kk * 4 + lq) ^ (m15 & 7)) * 8;
#pragma unroll
      for (int gq = 0; gq < 4; ++gq) {
        s16x8 B0 = *(const s16x8*)&Wl[0][gq][m15][cc];
        s16x8 B1 = *(const s16x8*)&Wl[1][gq][m15][cc];
        s16x8 B2 = *(const s16x8*)&Wl[2][gq][m15][cc];
        f32x4 t2 = acc[gq];
        t2 = MFMA_BF16(a1, B1, t2, 0, 0, 0);
        t2 = MFMA_BF16(a0, B2, t2, 0, 0, 0);
        t2 = MFMA_BF16(a2, B0, t2, 0, 0, 0);
        t2 = MFMA_BF16(a1, B0, t2, 0, 0, 0);
        t2 = MFMA_BF16(a0, B1, t2, 0, 0, 0);
        t2 = MFMA_BF16(a0, B0, t2, 0, 0, 0);
        acc[gq] = t2;
      }
      a0 = n0; a1 = n1; a2 = n2;
    }
    int t = dir ? (TN - 1 - s) : s;
#pragma unroll
    for (int r = 0; r < 4; ++r) {
      int brow = b0 + wv * 16 + r0 + r;
      float gi = acc[0][r] + xv[r][0];
      float gf = acc[1][r] + xv[r][1];
      float gg = acc[2][r] + xv[r][2];
      float go = acc[3][r] + xv[r][3];
      float cn = sigm(gf) * cx[r] + sigm(gi) * tanhf(gg);
      float hn = sigm(go) * tanhf(cn);
      cx[r] = cn;
      unsigned short q0v = bf_hi(hn);
      float rr1 = hn - bf_f(q0v);
      unsigned short q1v = bf_hi(rr1);
      unsigned short q2v = bf_hi(rr1 - bf_f(q1v));
      size_t ho = (size_t)brow * 256 + j;
      __builtin_nontemporal_store(q0v, &hw0[ho]);
      __builtin_nontemporal_store(q1v, &hw1[ho]);
      __builtin_nontemporal_store(q2v, &hw2[ho]);
      short q = (short)__float2int_rn(hn * 32767.f);
      if (mode == 0) {
        __builtin_nontemporal_store(q, &X[((size_t)brow * TN + t) * 512 + (dir << 8) + j]);
      } else if (mode == 1) {
        if (dir == 0) {
          if (t >= 256)
            __builtin_nontemporal_store(q, &X[((size_t)brow * TN + t) * 512 + j]);
          else
            __builtin_nontemporal_store(q, &Sf[((size_t)t * 256 + brow) * 256 + j]);
        } else {
          if (t < 256)
            __builtin_nontemporal_store(q, &X[((size_t)brow * TN + t) * 512 + 256 + j]);
          else
            __builtin_nontemporal_store(q, &Sr[((size_t)(t - 256) * 256 + brow) * 256 + j]);
        }
      } else {
        if (t == 0)
          __builtin_nontemporal_store(hn, &dec_in[(size_t)brow * 512 + (dir << 8) + j]);
      }
    }
    __threadfence();
    __syncthreads();
    if (tid == 0) {
      __hip_atomic_fetch_add(cnt, 1, __ATOMIC_RELEASE, __HIP_MEMORY_SCOPE_AGENT);
      int target = 16 * (s + 1);
      while (__hip_atomic_load(cnt, __ATOMIC_RELAXED, __HIP_MEMORY_SCOPE_AGENT) < target) {
        __builtin_amdgcn_s_sleep(1);
      }
    }
    __syncthreads();
    __threadfence();
  }
#pragma unroll
  for (int r = 0; r < 4; ++r)
    Cst[(size_t)dir * 65536 + (b0 + wv * 16 + r0 + r) * 256 + j16 + m15] = cx[r];
}

// ---------------- flush side buffers into X ----------------
__global__ void k_flush(short* __restrict__ X, const short* __restrict__ Sf,
                        const short* __restrict__ Sr) {
  int side = blockIdx.y;
  int idx = blockIdx.x * 256 + threadIdx.x;
  int t0 = idx >> 13;
  int b = (idx >> 5) & 255;
  int j0 = (idx & 31) * 8;
  if (side == 0) {
    *(s16x8*)&X[((size_t)b * TN + t0) * 512 + j0] =
        *(const s16x8*)&Sf[((size_t)t0 * 256 + b) * 256 + j0];
  } else {
    int t = 256 + t0;
    *(s16x8*)&X[((size_t)b * TN + t) * 512 + 256 + j0] =
        *(const s16x8*)&Sr[((size_t)t0 * 256 + b) * 256 + j0];
  }
}

// ======================= distributed-LDS decoder (round-13-verified) =======================
#define DWAIT(CTR, TARGET)                                                        \
  __syncthreads();                                                                \
  if (tid == 0) {                                                                 \
    while (__hip_atomic_load((CTR), __ATOMIC_RELAXED, __HIP_MEMORY_SCOPE_AGENT) < \
           (TARGET))                                                              \
      __builtin_amdgcn_s_sleep(1);                                                \
  }                                                                               \
  __syncthreads();                                                                \
  __threadfence();

#define DPOST(CTR)                                                                \
  __threadfence();                                                                \
  __syncthreads();                                                                \
  if (tid == 0)                                                                   \
    __hip_atomic_fetch_add((CTR), 1, __ATOMIC_RELEASE, __HIP_MEMORY_SCOPE_AGENT);

#define CMM(MT, CI)                                                               \
  {                                                                               \
    int cs_ = ((CI) ^ (m15 & 7)) * 8;                                             \
    _Pragma("unroll") for (int p = 0; p < 2; ++p) {                               \
      s16x8 B0 = *(const s16x8*)&W[((size_t)(0 * 2 + p) * 16 + m15) * KT + cs_];  \
      s16x8 B1 = *(const s16x8*)&W[((size_t)(1 * 2 + p) * 16 + m15) * KT + cs_];  \
      s16x8 B2 = *(const s16x8*)&W[((size_t)(2 * 2 + p) * 16 + m15) * KT + cs_];  \
      f32x4 t2 = acc[MT][p];                                                      \
      t2 = MFMA_BF16(a1, B1, t2, 0, 0, 0);                                        \
      t2 = MFMA_BF16(a0, B2, t2, 0, 0, 0);                                        \
      t2 = MFMA_BF16(a2, B0, t2, 0, 0, 0);                                        \
      t2 = MFMA_BF16(a1, B0, t2, 0, 0, 0);                                        \
      t2 = MFMA_BF16(a0, B1, t2, 0, 0, 0);                                        \
      t2 = MFMA_BF16(a0, B0, t2, 0, 0, 0);                                        \
      acc[MT][p] = t2;                                                            \
    }                                                                             \
  }

__global__ __launch_bounds__(512) void k_dec2(
    const float* __restrict__ dec_in0,
    const unsigned short* __restrict__ q0, const unsigned short* __restrict__ q1,
    const unsigned short* __restrict__ q2,
    const float* __restrict__ db, const float* __restrict__ pb,
    unsigned short* __restrict__ Dh, int* __restrict__ toksG,
    int* __restrict__ bar, float* __restrict__ out) {
  __shared__ unsigned short W[73728];   // 144 KB
  __shared__ float LG[8][256];
  __shared__ float rvv[8][16];
  __shared__ int rii[8][16];
  int tid = threadIdx.x, lane = tid & 63, wv = tid >> 6;
  int m15 = lane & 15, lq = lane >> 4, hk8 = lq * 8;
  int blk = blockIdx.x;
  int grp = blk >> 5;
  int gix = blk & 31;
  int j8 = gix * 8;
  int KT = (grp == 0) ? 768 : 512;
  int* c0 = bar + 0, *c1 = bar + 32, *c2 = bar + 64, *c3 = bar + 96;

  {
    int KC = KT >> 3;
    int nvec = 6 * 16 * KC;
    for (int v = tid; v < nvec; v += 512) {
      int c = v % KC;
      int r = (v / KC) & 15;
      int pp = v / (KC * 16);
      int pl = pp >> 1, p = pp & 1;
      int g = (2 * p + (r >> 3)) * 256 + j8 + (r & 7);
      int k = c * 8;
      size_t so;
      if (grp == 0)
        so = (k < 512) ? (size_t)OD0 + (size_t)g * 512 + k
                       : (size_t)ODH + (size_t)g * 256 + (k - 512);
      else if (grp == 1)
        so = (k < 256) ? (size_t)ODR + (size_t)g * 256 + k
                       : (size_t)ODH + 262144 + (size_t)g * 256 + (k - 256);
      else
        so = (k < 256) ? (size_t)ODR + 262144 + (size_t)g * 256 + k
                       : (size_t)ODH + 524288 + (size_t)g * 256 + (k - 256);
      const unsigned short* qs = (pl == 0) ? q0 : ((pl == 1) ? q1 : q2);
      int cs = c ^ (r & 7);
      *(u16x8*)&W[((size_t)pp * 16 + r) * KT + (size_t)cs * 8] = *(const u16x8*)&qs[so];
    }
  }
  __syncthreads();

  int cc8 = m15 & 7;
  int jcol = j8 + cc8;
  float bI = db[grp * 1024 + jcol];
  float bF = db[grp * 1024 + 256 + jcol];
  float bG = db[grp * 1024 + 512 + jcol];
  float bO = db[grp * 1024 + 768 + jcol];
  f32x4 cx[2];
  cx[0] = (f32x4){0.f, 0.f, 0.f, 0.f};
  cx[1] = (f32x4){0.f, 0.f, 0.f, 0.f};

  int gb = gix * 8;
  int mrow = m15 & 7;
  int r0q = lq * 4;
  bool act = (r0q < 8);

  for (int t = 0; t < LDEC; ++t) {
    int pw = (t & 1) ^ 1, pr = t & 1;
    if (grp == 0) { DWAIT(c3, 32 * t) }
    else if (grp == 1) { DWAIT(c0, 32 * (t + 1)) }
    else { DWAIT(c1, 32 * (t + 1)) }

    f32x4 acc[2][2];
#pragma unroll
    for (int mt = 0; mt < 2; ++mt)
#pragma unroll
      for (int p = 0; p < 2; ++p) acc[mt][p] = (f32x4){0.f, 0.f, 0.f, 0.f};

    if (grp == 0) {
      if (t == 0) {
        for (int kk = 0; kk < 16; ++kk) {
#pragma unroll
          for (int mt = 0; mt < 2; ++mt) {
            int browA = wv * 32 + mt * 16 + m15;
            const float* src = dec_in0 + (size_t)browA * 512 + kk * 32 + hk8;
            s16x8 a0, a1, a2;
#pragma unroll
            for (int e = 0; e < 8; ++e) {
              float v = src[e];
              unsigned short t0 = bf_hi(v);
              float r1 = v - bf_f(t0);
              unsigned short t1 = bf_hi(r1);
              a0[e] = (short)t0; a1[e] = (short)t1; a2[e] = (short)bf_hi(r1 - bf_f(t1));
            }
            CMM(mt, kk * 4 + lq)
          }
        }
      } else {
        for (int kk = 0; kk < 8; ++kk) {
#pragma unroll
          for (int mt = 0; mt < 2; ++mt) {
            int browA = wv * 32 + mt * 16 + m15;
            int tok = toksG[browA];
            size_t eo = (size_t)OEM + (size_t)tok * 256 + kk * 32 + hk8;
            s16x8 a0 = *(const s16x8*)&q0[eo];
            s16x8 a1 = *(const s16x8*)&q1[eo];
            s16x8 a2 = *(const s16x8*)&q2[eo];
            CMM(mt, kk * 4 + lq)
          }
        }
      }
    } else {
      const unsigned short* x0p = Dh + (size_t)(((grp - 1) * 2 + pw) * 3 + 0) * 65536;
      const unsigned short* x1p = Dh + (size_t)(((grp - 1) * 2 + pw) * 3 + 1) * 65536;
      const unsigned short* x2p = Dh + (size_t)(((grp - 1) * 2 + pw) * 3 + 2) * 65536;
      for (int kk = 0; kk < 8; ++kk) {
#pragma unroll
        for (int mt = 0; mt < 2; ++mt) {
          size_t ao = (size_t)(wv * 32 + mt * 16 + m15) * 256 + kk * 32 + hk8;
          s16x8 a0 = *(const s16x8*)&x0p[ao];
          s16x8 a1 = *(const s16x8*)&x1p[ao];
          s16x8 a2 = *(const s16x8*)&x2p[ao];
          CMM(mt, kk * 4 + lq)
        }
      }
    }
    {
      int cb = (grp == 0) ? 64 : 32;
      const unsigned short* h0p = Dh + (size_t)((grp * 2 + pr) * 3 + 0) * 65536;
      const unsigned short* h1p = Dh + (size_t)((grp * 2 + pr) * 3 + 1) * 65536;
      const unsigned short* h2p = Dh + (size_t)((grp * 2 + pr) * 3 + 2) * 65536;
      for (int kk = 0; kk < 8; ++kk) {
#pragma unroll
        for (int mt = 0; mt < 2; ++mt) {
          size_t ao = (size_t)(wv * 32 + mt * 16 + m15) * 256 + kk * 32 + hk8;
          s16x8 a0 = *(const s16x8*)&h0p[ao];
          s16x8 a1 = *(const s16x8*)&h1p[ao];
          s16x8 a2 = *(const s16x8*)&h2p[ao];
          CMM(mt, cb + kk * 4 + lq)
        }
      }
    }
    {
      unsigned short* hw0 = Dh + (size_t)((grp * 2 + pw) * 3 + 0) * 65536;
      unsigned short* hw1 = Dh + (size_t)((grp * 2 + pw) * 3 + 1) * 65536;
      unsigned short* hw2 = Dh + (size_t)((grp * 2 + pw) * 3 + 2) * 65536;
#pragma unroll
      for (int mt = 0; mt < 2; ++mt) {
        f32x4 fx, ox;
#pragma unroll
        for (int e = 0; e < 4; ++e) {
          fx[e] = __shfl_xor(acc[mt][0][e], 8);
          ox[e] = __shfl_xor(acc[mt][1][e], 8);
        }
        if (m15 < 8) {
#pragma unroll
          for (int r = 0; r < 4; ++r) {
            int brow = wv * 32 + mt * 16 + lq * 4 + r;
            float gi = acc[mt][0][r] + bI;
            float gf = fx[r] + bF;
            float gg = acc[mt][1][r] + bG;
            float go = ox[r] + bO;
            float cn = sigm(gf) * cx[mt][r] + sigm(gi) * tanhf(gg);
            float hn = sigm(go) * tanhf(cn);
            cx[mt][r] = cn;
            unsigned short p0v = bf_hi(hn);
            float rr1 = hn - bf_f(p0v);
            unsigned short p1v = bf_hi(rr1);
            unsigned short p2v = bf_hi(rr1 - bf_f(p1v));
            size_t ho = (size_t)brow * 256 + jcol;
            hw0[ho] = p0v; hw1[ho] = p1v; hw2[ho] = p2v;
          }
        }
      }
    }
    if (grp == 0) { DPOST(c0) }
    else if (grp == 1) { DPOST(c1) }
    else { DPOST(c2) }

    if (grp == 2) {
      DWAIT(c2, 32 * (t + 1))
      unsigned short* H2 = &W[49152];
      for (int i = tid; i < 6144; i += 512) {
        int pl = i / 2048;
        int rem = i - pl * 2048;
        int row = rem >> 8, col = rem & 255;
        H2[pl * 2112 + row * 264 + col] =
            Dh[(size_t)((2 * 2 + pw) * 3 + pl) * 65536 + (size_t)(gb + row) * 256 + col];
      }
      __syncthreads();
      f32x4 pacc[2];
#pragma unroll
      for (int jj = 0; jj < 2; ++jj) pacc[jj] = (f32x4){0.f, 0.f, 0.f, 0.f};
      for (int kk = 0; kk < 8; ++kk) {
        s16x8 a0 = *(const s16x8*)&H2[0 * 2112 + mrow * 264 + kk * 32 + hk8];
        s16x8 a1 = *(const s16x8*)&H2[1 * 2112 + mrow * 264 + kk * 32 + hk8];
        s16x8 a2 = *(const s16x8*)&H2[2 * 2112 + mrow * 264 + kk * 32 + hk8];
#pragma unroll
        for (int jj = 0; jj < 2; ++jj) {
          int v = wv * 32 + jj * 16 + m15;
          size_t wo = OPJ + (size_t)v * 256 + kk * 32 + hk8;
          MF6(pacc[jj], q0, q1, q2, wo)
        }
      }
      if (act) {
#pragma unroll
        for (int jj = 0; jj < 2; ++jj) {
          int v = wv * 32 + jj * 16 + m15;
          float pbv = pb[v];
#pragma unroll
          for (int r = 0; r < 4; ++r) LG[r0q + r][v] = pacc[jj][r] + pbv;
        }
      }
      __syncthreads();
      for (int i = tid; i < 2048; i += 512) {
        int row = i >> 8, v = i & 255;
        out[((size_t)(gb + row) * LDEC + t) * 256 + v] = LG[row][v];
      }
      if (tid < 128) {
        int prow = tid >> 4, pp = tid & 15;
        float bv = LG[prow][pp * 16];
        int bidx = pp * 16;
        for (int i2 = 1; i2 < 16; ++i2) {
          float v2 = LG[prow][pp * 16 + i2];
          if (v2 > bv) { bv = v2; bidx = pp * 16 + i2; }
        }
        rvv[prow][pp] = bv;
        rii[prow][pp] = bidx;
      }
      __syncthreads();
      if (tid < 8) {
        float best = rvv[tid][0];
        int bi = rii[tid][0];
        for (int qq = 1; qq < 16; ++qq) {
          float v2 = rvv[tid][qq];
          int ii = rii[tid][qq];
          if (v2 > best || (v2 == best && ii < bi)) { best = v2; bi = ii; }
        }
        toksG[gb + tid] = bi;
      }
      DPOST(c3)
    }
  }
}

extern "C" void kernel_launch(void* const* d_in, const int* in_sizes, int n_in,
                              void* d_out, int out_size, void* d_ws, size_t ws_size,
                              hipStream_t stream) {
  const int* text = (const int*)d_in[0];
  const float* emb = (const float*)d_in[2];
  const float* w_ih_l0 = (const float*)d_in[3];
  const float* w_hh_l0 = (const float*)d_in[4];
  const float* b_l0 = (const float*)d_in[5];
  const float* w_ih_r = (const float*)d_in[6];
  const float* w_hh_r = (const float*)d_in[7];
  const float* b_r = (const float*)d_in[8];
  const float* dwih0 = (const float*)d_in[9];
  const float* dwihr = (const float*)d_in[10];
  const float* dwhh = (const float*)d_in[11];
  const float* db = (const float*)d_in[12];
  const float* pw = (const float*)d_in[13];
  const float* pb = (const float*)d_in[14];

  char* ws = (char*)d_ws;
  short *X, *Sf, *Sr;
  unsigned short *wihh, *wihl, *whp0, *whp1, *whp2, *embh, *embl, *Hg, *Dh;
  unsigned short *q0, *q1, *q2;
  float *XG, *Cst, *dec_in;
  int *bar, *toksG;
  int W = 0;
  for (int Wv = 8; Wv >= 4 && W == 0; Wv >>= 1) {
    size_t off = 0;
    X    = (short*)(ws + off);          off += (size_t)Bsz * TN * 512 * 2;
    Sf   = (short*)(ws + off);          off += (size_t)256 * Bsz * 256 * 2;
    Sr   = (short*)(ws + off);          off += (size_t)256 * Bsz * 256 * 2;
    XG   = (float*)(ws + off);          off += (size_t)2 * Wv * 262144 * 4;
    wihh = (unsigned short*)(ws + off); off += 2621440ull * 2;
    wihl = (unsigned short*)(ws + off); off += 2621440ull * 2;
    whp0 = (unsigned short*)(ws + off); off += 1572864ull * 2;
    whp1 = (unsigned short*)(ws + off); off += 1572864ull * 2;
    whp2 = (unsigned short*)(ws + off); off += 1572864ull * 2;
    embh = (unsigned short*)(ws + off); off += 65536 * 2;
    embl = (unsigned short*)(ws + off); off += 65536 * 2;
    q0   = (unsigned short*)(ws + off); off += 1966080ull * 2;
    q1   = (unsigned short*)(ws + off); off += 1966080ull * 2;
    q2   = (unsigned short*)(ws + off); off += 1966080ull * 2;
    Hg   = (unsigned short*)(ws + off); off += 786432ull * 2;
    Dh   = (unsigned short*)(ws + off); off += 1179648ull * 2;
    Cst  = (float*)(ws + off);          off += (size_t)2 * Bsz * Hh * 4;
    dec_in = (float*)(ws + off);        off += (size_t)Bsz * 512 * 4;
    toksG = (int*)(ws + off);           off += 1024;
    bar  = (int*)(ws + off);            off += 2048;
    if (ws_size >= off) W = Wv;
  }
  if (W == 0) {
    float dval = 1000.0f + (float)(ws_size >> 20);
    k_fill<<<(out_size + 255) / 256, 256, 0, stream>>>((float*)d_out, out_size, dval);
    return;
  }

  k_zeroi<<<1, 512, 0, stream>>>(bar, 512);
  k_fill<<<2304, 256, 0, stream>>>((float*)Dh, 589824, 0.f);

  k_split<<<2048, 256, 0, stream>>>(w_ih_l0, wihh, wihl, 524288);
  k_split<<<8192, 256, 0, stream>>>(w_ih_r, wihh + 524288, wihl + 524288, 2097152);
  k_split<<<256, 256, 0, stream>>>(emb, embh, embl, 65536);
  k_split3<<<2048, 256, 0, stream>>>(w_hh_l0, whp0, whp1, whp2, 524288);
  k_split3<<<4096, 256, 0, stream>>>(w_hh_r, whp0 + 524288, whp1 + 524288, whp2 + 524288, 1048576);
  k_split3<<<2048, 256, 0, stream>>>(dwih0, q0 + OD0, q1 + OD0, q2 + OD0, 524288);
  k_split3<<<2048, 256, 0, stream>>>(dwihr, q0 + ODR, q1 + ODR, q2 + ODR, 524288);
  k_split3<<<3072, 256, 0, stream>>>(dwhh, q0 + ODH, q1 + ODH, q2 + ODH, 786432);
  k_split3<<<256, 256, 0, stream>>>(pw, q0 + OPJ, q1 + OPJ, q2 + OPJ, 65536);
  k_split3<<<256, 256, 0, stream>>>(emb, q0 + OEM, q1 + OEM, q2 + OEM, 65536);

  for (int l = 0; l < 3; ++l) {
    int K = (l == 0) ? 256 : 512;
    const unsigned short *wih_h, *wih_l;
    int wstride;
    const float* bias;
    if (l == 0) {
      wih_h = wihh; wih_l = wihl; wstride = 262144;
      bias = b_l0;
    } else {
      size_t wo = 524288 + (size_t)(l - 1) * 1048576;
      wih_h = wihh + wo; wih_l = wihl + wo; wstride = 524288;
      bias = b_r + (size_t)(l - 1) * 2048;
    }
    size_t wl_off = (size_t)((l == 0) ? 0 : 2 * l) * 262144;
    int mode = (l == 2) ? 2 : ((l == 1) ? 1 : 0);
    k_fill<<<1536, 256, 0, stream>>>((float*)Hg, 393216, 0.f);
    int nwin = TN / W;
    for (int ch = 0; ch < nwin; ++ch) {
      int s0 = ch * W;
      int both = !(l == 2 && ch > 0);
      int Z = both ? 2 * W : W;
      k_gemm<<<dim3(4, 8, Z), 256, 0, stream>>>(X, text, embh, embl, (l == 0) ? 1 : 0, K,
                                                wih_h, wih_l, wstride, bias, XG, s0, both);
      k_wstep<<<dim3(16, 2, 2), 512, 0, stream>>>(XG, whp0 + wl_off, whp1 + wl_off,
                                                  whp2 + wl_off, Hg, Cst,
                                                  X, Sf, Sr, dec_in, bar + l * 128, s0, W, mode);
    }
    if (l == 1) k_flush<<<dim3(8192, 2), 256, 0, stream>>>(X, Sf, Sr);
  }

  k_dec2<<<96, 512, 0, stream>>>(dec_in, q0, q1, q2, db, pb, Dh, toksG,
                                 bar + 384, (float*)d_out);

  // ===== PROBE: rerun layer 0 twice (writes are dead; d_out untouched) =====
  // dur = base(67.7) + 2*T_l0. Counters+Hg re-zeroed so sync behavior matches
  // the real pass. X is overwritten with layer-0 output — nothing reads it after.
  for (int rep = 0; rep < 2; ++rep) {
    k_zeroi<<<1, 512, 0, stream>>>(bar, 512);
    k_fill<<<1536, 256, 0, stream>>>((float*)Hg, 393216, 0.f);
    for (int ch = 0; ch < TN / W; ++ch) {
      int s0 = ch * W;
      k_gemm<<<dim3(4, 8, 2 * W), 256, 0, stream>>>(X, text, embh, embl, 1, 256,
                                                    wihh, wihl, 262144, b_l0, XG, s0, 1);
      k_wstep<<<dim3(16, 2, 2), 512, 0, stream>>>(XG, whp0, whp1, whp2, Hg, Cst,
                                                  X, Sf, Sr, dec_in, bar, s0, W, 0);
    }
  }
}

// Round 15
// 49582.629 us; speedup vs baseline: 2.1538x; 2.1538x over previous
//
#include <hip/hip_runtime.h>
#include <hip/hip_bf16.h>

#define Hh 256
#define G4 1024
#define Bsz 256
#define TN 512
#define LDEC 100

// decoder weight-plane element offsets
#define OD0 0
#define ODR 524288
#define ODH 1048576
#define OPJ 1835008
#define OEM 1900544

typedef __attribute__((ext_vector_type(4))) float f32x4;
typedef __attribute__((ext_vector_type(8))) short s16x8;
typedef __attribute__((ext_vector_type(8))) unsigned short u16x8;

__device__ __forceinline__ unsigned short bf_hi(float v) {
  __hip_bfloat16 h = __float2bfloat16(v);
  return *(unsigned short*)&h;
}
__device__ __forceinline__ float bf_f(unsigned short u) {
  unsigned int x = ((unsigned int)u) << 16;
  return *(float*)&x;
}
__device__ __forceinline__ float sigm(float x) { return 1.f / (1.f + expf(-x)); }

// ---------------- fills ----------------
__global__ void k_fill(float* __restrict__ p, int n, float v) {
  int i = blockIdx.x * 256 + threadIdx.x;
  if (i < n) p[i] = v;
}

// ---------------- split fp32 -> 2-plane bf16 ----------------
__global__ void k_split(const float* __restrict__ src, unsigned short* __restrict__ hi,
                        unsigned short* __restrict__ lo, int n) {
  int i = blockIdx.x * 256 + threadIdx.x;
  if (i < n) {
    float v = src[i];
    unsigned short h = bf_hi(v);
    hi[i] = h;
    lo[i] = bf_hi(v - bf_f(h));
  }
}

// ---------------- split fp32 -> 3-plane bf16 ----------------
__global__ void k_split3(const float* __restrict__ src, unsigned short* __restrict__ p0,
                         unsigned short* __restrict__ p1, unsigned short* __restrict__ p2,
                         int n) {
  int i = blockIdx.x * 256 + threadIdx.x;
  if (i < n) {
    float v = src[i];
    unsigned short a = bf_hi(v);
    float r1 = v - bf_f(a);
    unsigned short b = bf_hi(r1);
    float r2 = r1 - bf_f(b);
    p0[i] = a;
    p1[i] = b;
    p2[i] = bf_hi(r2);
  }
}

// ---------------- xg GEMM with fused A staging (round-6-verified) ----------------
__global__ __launch_bounds__(256) void k_gemm(
    const short* __restrict__ X, const int* __restrict__ text,
    const unsigned short* __restrict__ eh, const unsigned short* __restrict__ el, int l0,
    int K,
    const unsigned short* __restrict__ wh_, const unsigned short* __restrict__ wl_, int wstride,
    const float* __restrict__ bias, float* __restrict__ xg, int s0, int both) {
  int mt = blockIdx.x, nt = blockIdx.y, z = blockIdx.z;
  int slot, dir, w;
  if (both) { slot = z; dir = z & 1; w = z >> 1; }
  else      { slot = z * 2 + 1; dir = 1; w = z; }
  int s = s0 + w;
  int t = dir ? (TN - 1 - s) : s;
  const unsigned short* wh = wh_ + (size_t)dir * wstride;
  const unsigned short* wl = wl_ + (size_t)dir * wstride;
  const float* bp = bias + dir * G4;
  __shared__ unsigned short Ah[64][40], Al[64][40], Bh[128][40], Bl[128][40];
  int tid = threadIdx.x, wave = tid >> 6, lane = tid & 63;
  f32x4 acc[8];
#pragma unroll
  for (int i = 0; i < 8; ++i) acc[i] = (f32x4){0.f, 0.f, 0.f, 0.f};

  int ar = tid >> 2, akq = (tid & 3) * 8;
  int brow = mt * 64 + ar;
  const unsigned short *aeh = nullptr, *ael = nullptr;
  const short* ax = nullptr;
  if (l0) {
    int tok = text[brow * TN + t];
    aeh = eh + tok * 256 + akq;
    ael = el + tok * 256 + akq;
  } else {
    ax = X + ((size_t)brow * TN + t) * 512 + akq;
  }
  int br = tid >> 1, bkq = (tid & 1) * 16;
  int g = nt * 128 + br;
  const unsigned short* bsrch = wh + (size_t)g * K + bkq;
  const unsigned short* bsrcl = wl + (size_t)g * K + bkq;

  for (int kk = 0; kk < K; kk += 32) {
    __syncthreads();
    if (l0) {
      *(u16x8*)&Ah[ar][akq] = *(const u16x8*)(aeh + kk);
      *(u16x8*)&Al[ar][akq] = *(const u16x8*)(ael + kk);
    } else {
      s16x8 sv = *(const s16x8*)(ax + kk);
      u16x8 hv, lv;
#pragma unroll
      for (int j = 0; j < 8; ++j) {
        float a = (float)sv[j] * (1.f / 32767.f);
        unsigned short h = bf_hi(a);
        hv[j] = h;
        lv[j] = bf_hi(a - bf_f(h));
      }
      *(u16x8*)&Ah[ar][akq] = hv;
      *(u16x8*)&Al[ar][akq] = lv;
    }
    *(u16x8*)&Bh[br][bkq]      = *(const u16x8*)(bsrch + kk);
    *(u16x8*)&Bh[br][bkq + 8]  = *(const u16x8*)(bsrch + kk + 8);
    *(u16x8*)&Bl[br][bkq]      = *(const u16x8*)(bsrcl + kk);
    *(u16x8*)&Bl[br][bkq + 8]  = *(const u16x8*)(bsrcl + kk + 8);
    __syncthreads();

    int m = wave * 16 + (lane & 15);
    int kq = (lane >> 4) * 8;
    s16x8 ah = *(s16x8*)&Ah[m][kq];
    s16x8 al = *(s16x8*)&Al[m][kq];
#pragma unroll
    for (int nf = 0; nf < 8; ++nf) {
      s16x8 bh = *(s16x8*)&Bh[nf * 16 + (lane & 15)][kq];
      s16x8 bl = *(s16x8*)&Bl[nf * 16 + (lane & 15)][kq];
      acc[nf] = __builtin_amdgcn_mfma_f32_16x16x32_bf16(ah, bh, acc[nf], 0, 0, 0);
      acc[nf] = __builtin_amdgcn_mfma_f32_16x16x32_bf16(al, bh, acc[nf], 0, 0, 0);
      acc[nf] = __builtin_amdgcn_mfma_f32_16x16x32_bf16(ah, bl, acc[nf], 0, 0, 0);
    }
  }
  int col = lane & 15, rq = (lane >> 4) * 4;
  float* outp = xg + (size_t)slot * 262144;
#pragma unroll
  for (int nf = 0; nf < 8; ++nf) {
    int gg = nt * 128 + nf * 16 + col;
    float bv = bp[gg];
#pragma unroll
    for (int r = 0; r < 4; ++r) {
      int b = mt * 64 + wave * 16 + rq + r;
      outp[(size_t)b * 1024 + gg] = acc[nf][r] + bv;
    }
  }
}

// 6-product accumulation macro (streamed-B) — ascending magnitude
#define MF6(ACC, P0, P1, P2, WO)                                                         \
  {                                                                                      \
    s16x8 bf0 = *(const s16x8*)&(P0)[WO];                                                \
    s16x8 bf1 = *(const s16x8*)&(P1)[WO];                                                \
    s16x8 bf2 = *(const s16x8*)&(P2)[WO];                                                \
    ACC = __builtin_amdgcn_mfma_f32_16x16x32_bf16(a1, bf1, ACC, 0, 0, 0);                \
    ACC = __builtin_amdgcn_mfma_f32_16x16x32_bf16(a0, bf2, ACC, 0, 0, 0);                \
    ACC = __builtin_amdgcn_mfma_f32_16x16x32_bf16(a2, bf0, ACC, 0, 0, 0);                \
    ACC = __builtin_amdgcn_mfma_f32_16x16x32_bf16(a1, bf0, ACC, 0, 0, 0);                \
    ACC = __builtin_amdgcn_mfma_f32_16x16x32_bf16(a0, bf1, ACC, 0, 0, 0);                \
    ACC = __builtin_amdgcn_mfma_f32_16x16x32_bf16(a0, bf0, ACC, 0, 0, 0);                \
  }

#define MFMA_BF16 __builtin_amdgcn_mfma_f32_16x16x32_bf16

// ---------------- window recurrence — contention-free arrival-slot barrier ----------------
// Block (jt, bs, dir): h cols [jt*16,+16) for batch rows [bs*128,+128).
// Barrier per step over 16 jt-blocks of (bs,dir): each block release-fences,
// STOREs its epoch to its own 128B slot (no RMW), then 16 lanes poll the 16
// slots in parallel; acquire fence after. Last step of window: no barrier
// (kernel boundary syncs). bar layout: slot = bar + ((dir*2+bs)*16 + jt)*32.
__global__ __launch_bounds__(512) void k_wstep(
    const float* __restrict__ xg,
    const unsigned short* __restrict__ w0, const unsigned short* __restrict__ w1,
    const unsigned short* __restrict__ w2,
    unsigned short* __restrict__ Hg,   // [dir][par][plane][256][256] ushort
    float* __restrict__ Cst,
    short* __restrict__ X, short* __restrict__ Sf, short* __restrict__ Sr,
    float* __restrict__ dec_in, int* __restrict__ bar, int s0, int W, int mode) {
  int jt = blockIdx.x, bs = blockIdx.y, dir = blockIdx.z;
  if (mode == 2 && dir == 0 && s0 != 0) return;
  int nsteps = (mode == 2 && dir == 0) ? 1 : W;
  int j16 = jt * 16;
  int b0 = bs * 128;
  const unsigned short* wp0 = w0 + dir * 262144;
  const unsigned short* wp1 = w1 + dir * 262144;
  const unsigned short* wp2 = w2 + dir * 262144;
  int* gbase = bar + ((dir * 2 + bs) * 16) * 32;
  int* slot = gbase + jt * 32;

  __shared__ unsigned short Wl[3][4][16][256];
  int tid = threadIdx.x, lane = tid & 63, wv = tid >> 6;
  int m15 = lane & 15, lq = lane >> 4, hk8 = lq * 8, r0 = lq * 4;

  for (int v = tid; v < 6144; v += 512) {
    int pl = v / 2048;
    int rem = v - pl * 2048;
    int gq = rem >> 9;
    int r = (rem >> 5) & 15;
    int c = rem & 31;
    const unsigned short* wp = (pl == 0) ? wp0 : ((pl == 1) ? wp1 : wp2);
    *(u16x8*)&Wl[pl][gq][r][(c ^ (r & 7)) * 8] =
        *(const u16x8*)&wp[((size_t)(gq * 256 + j16 + r)) * 256 + c * 8];
  }
  f32x4 cx;
  if (s0 == 0) {
    cx = (f32x4){0.f, 0.f, 0.f, 0.f};
  } else {
#pragma unroll
    for (int r = 0; r < 4; ++r)
      cx[r] = Cst[(size_t)dir * 65536 + (b0 + wv * 16 + r0 + r) * 256 + j16 + m15];
  }
  __syncthreads();

  int j = j16 + m15;
  for (int w = 0; w < nsteps; ++w) {
    int s = s0 + w;
    int p0 = s & 1, p1 = p0 ^ 1;
    const float* xgp = xg + (size_t)(2 * w + dir) * 262144;
    const unsigned short* hr0 = Hg + ((size_t)(dir * 2 + p0) * 3 + 0) * 65536;
    const unsigned short* hr1 = Hg + ((size_t)(dir * 2 + p0) * 3 + 1) * 65536;
    const unsigned short* hr2 = Hg + ((size_t)(dir * 2 + p0) * 3 + 2) * 65536;
    unsigned short* hw0 = Hg + ((size_t)(dir * 2 + p1) * 3 + 0) * 65536;
    unsigned short* hw1 = Hg + ((size_t)(dir * 2 + p1) * 3 + 1) * 65536;
    unsigned short* hw2 = Hg + ((size_t)(dir * 2 + p1) * 3 + 2) * 65536;

    float xv[4][4];
#pragma unroll
    for (int r = 0; r < 4; ++r) {
      const float* xr = xgp + (size_t)(b0 + wv * 16 + r0 + r) * 1024 + j;
      xv[r][0] = xr[0];
      xv[r][1] = xr[256];
      xv[r][2] = xr[512];
      xv[r][3] = xr[768];
    }

    f32x4 acc[4];
#pragma unroll
    for (int gq = 0; gq < 4; ++gq) acc[gq] = (f32x4){0.f, 0.f, 0.f, 0.f};

    size_t hbase = (size_t)(b0 + wv * 16 + m15) * 256 + hk8;
    s16x8 a0 = *(const s16x8*)&hr0[hbase];
    s16x8 a1 = *(const s16x8*)&hr1[hbase];
    s16x8 a2 = *(const s16x8*)&hr2[hbase];
#pragma unroll
    for (int kk = 0; kk < 8; ++kk) {
      s16x8 n0, n1, n2;
      if (kk < 7) {
        n0 = *(const s16x8*)&hr0[hbase + (kk + 1) * 32];
        n1 = *(const s16x8*)&hr1[hbase + (kk + 1) * 32];
        n2 = *(const s16x8*)&hr2[hbase + (kk + 1) * 32];
      }
      int cc = ((kk * 4 + lq) ^ (m15 & 7)) * 8;
#pragma unroll
      for (int gq = 0; gq < 4; ++gq) {
        s16x8 B0 = *(const s16x8*)&Wl[0][gq][m15][cc];
        s16x8 B1 = *(const s16x8*)&Wl[1][gq][m15][cc];
        s16x8 B2 = *(const s16x8*)&Wl[2][gq][m15][cc];
        f32x4 t2 = acc[gq];
        t2 = MFMA_BF16(a1, B1, t2, 0, 0, 0);
        t2 = MFMA_BF16(a0, B2, t2, 0, 0, 0);
        t2 = MFMA_BF16(a2, B0, t2, 0, 0, 0);
        t2 = MFMA_BF16(a1, B0, t2, 0, 0, 0);
        t2 = MFMA_BF16(a0, B1, t2, 0, 0, 0);
        t2 = MFMA_BF16(a0, B0, t2, 0, 0, 0);
        acc[gq] = t2;
      }
      a0 = n0; a1 = n1; a2 = n2;
    }
    int t = dir ? (TN - 1 - s) : s;
#pragma unroll
    for (int r = 0; r < 4; ++r) {
      int brow = b0 + wv * 16 + r0 + r;
      float gi = acc[0][r] + xv[r][0];
      float gf = acc[1][r] + xv[r][1];
      float gg = acc[2][r] + xv[r][2];
      float go = acc[3][r] + xv[r][3];
      float cn = sigm(gf) * cx[r] + sigm(gi) * tanhf(gg);
      float hn = sigm(go) * tanhf(cn);
      cx[r] = cn;
      unsigned short q0v = bf_hi(hn);
      float rr1 = hn - bf_f(q0v);
      unsigned short q1v = bf_hi(rr1);
      unsigned short q2v = bf_hi(rr1 - bf_f(q1v));
      size_t ho = (size_t)brow * 256 + j;
      __builtin_nontemporal_store(q0v, &hw0[ho]);
      __builtin_nontemporal_store(q1v, &hw1[ho]);
      __builtin_nontemporal_store(q2v, &hw2[ho]);
      short q = (short)__float2int_rn(hn * 32767.f);
      if (mode == 0) {
        __builtin_nontemporal_store(q, &X[((size_t)brow * TN + t) * 512 + (dir << 8) + j]);
      } else if (mode == 1) {
        if (dir == 0) {
          if (t >= 256)
            __builtin_nontemporal_store(q, &X[((size_t)brow * TN + t) * 512 + j]);
          else
            __builtin_nontemporal_store(q, &Sf[((size_t)t * 256 + brow) * 256 + j]);
        } else {
          if (t < 256)
            __builtin_nontemporal_store(q, &X[((size_t)brow * TN + t) * 512 + 256 + j]);
          else
            __builtin_nontemporal_store(q, &Sr[((size_t)(t - 256) * 256 + brow) * 256 + j]);
        }
      } else {
        if (t == 0)
          __builtin_nontemporal_store(hn, &dec_in[(size_t)brow * 512 + (dir << 8) + j]);
      }
    }
    // ---- contention-free barrier (skipped on last step: kernel boundary syncs) ----
    if (w < nsteps - 1) {
      __builtin_amdgcn_fence(__ATOMIC_RELEASE, "agent");   // drain + wbl2 only
      __syncthreads();
      if (tid == 0)
        __hip_atomic_store(slot, s + 1, __ATOMIC_RELAXED, __HIP_MEMORY_SCOPE_AGENT);
      if (tid < 16) {
        while (__hip_atomic_load(gbase + tid * 32, __ATOMIC_RELAXED,
                                 __HIP_MEMORY_SCOPE_AGENT) < s + 1) {}
      }
      __syncthreads();
      __builtin_amdgcn_fence(__ATOMIC_ACQUIRE, "agent");   // inv only
    }
  }
#pragma unroll
  for (int r = 0; r < 4; ++r)
    Cst[(size_t)dir * 65536 + (b0 + wv * 16 + r0 + r) * 256 + j16 + m15] = cx[r];
}

// ---------------- flush side buffers into X ----------------
__global__ void k_flush(short* __restrict__ X, const short* __restrict__ Sf,
                        const short* __restrict__ Sr) {
  int side = blockIdx.y;
  int idx = blockIdx.x * 256 + threadIdx.x;
  int t0 = idx >> 13;
  int b = (idx >> 5) & 255;
  int j0 = (idx & 31) * 8;
  if (side == 0) {
    *(s16x8*)&X[((size_t)b * TN + t0) * 512 + j0] =
        *(const s16x8*)&Sf[((size_t)t0 * 256 + b) * 256 + j0];
  } else {
    int t = 256 + t0;
    *(s16x8*)&X[((size_t)b * TN + t) * 512 + 256 + j0] =
        *(const s16x8*)&Sr[((size_t)t0 * 256 + b) * 256 + j0];
  }
}

// ======================= distributed-LDS decoder (arrival-slot barriers) ==============
#define DWAITA(BASE, TARGET)                                                      \
  __syncthreads();                                                                \
  if (tid < 32) {                                                                 \
    while (__hip_atomic_load((BASE) + tid * 32, __ATOMIC_RELAXED,                 \
                             __HIP_MEMORY_SCOPE_AGENT) < (TARGET)) {}             \
  }                                                                               \
  __syncthreads();                                                                \
  __builtin_amdgcn_fence(__ATOMIC_ACQUIRE, "agent");

#define DPOSTA(BASE, VAL)                                                         \
  __builtin_amdgcn_fence(__ATOMIC_RELEASE, "agent");                              \
  __syncthreads();                                                                \
  if (tid == 0)                                                                   \
    __hip_atomic_store((BASE) + gix * 32, (VAL), __ATOMIC_RELAXED,                \
                       __HIP_MEMORY_SCOPE_AGENT);

#define CMM(MT, CI)                                                               \
  {                                                                               \
    int cs_ = ((CI) ^ (m15 & 7)) * 8;                                             \
    _Pragma("unroll") for (int p = 0; p < 2; ++p) {                               \
      s16x8 B0 = *(const s16x8*)&W[((size_t)(0 * 2 + p) * 16 + m15) * KT + cs_];  \
      s16x8 B1 = *(const s16x8*)&W[((size_t)(1 * 2 + p) * 16 + m15) * KT + cs_];  \
      s16x8 B2 = *(const s16x8*)&W[((size_t)(2 * 2 + p) * 16 + m15) * KT + cs_];  \
      f32x4 t2 = acc[MT][p];                                                      \
      t2 = MFMA_BF16(a1, B1, t2, 0, 0, 0);                                        \
      t2 = MFMA_BF16(a0, B2, t2, 0, 0, 0);                                        \
      t2 = MFMA_BF16(a2, B0, t2, 0, 0, 0);                                        \
      t2 = MFMA_BF16(a1, B0, t2, 0, 0, 0);                                        \
      t2 = MFMA_BF16(a0, B1, t2, 0, 0, 0);                                        \
      t2 = MFMA_BF16(a0, B0, t2, 0, 0, 0);                                        \
      acc[MT][p] = t2;                                                            \
    }                                                                             \
  }

__global__ __launch_bounds__(512) void k_dec2(
    const float* __restrict__ dec_in0,
    const unsigned short* __restrict__ q0, const unsigned short* __restrict__ q1,
    const unsigned short* __restrict__ q2,
    const float* __restrict__ db, const float* __restrict__ pb,
    unsigned short* __restrict__ Dh, int* __restrict__ toksG,
    int* __restrict__ bar, float* __restrict__ out) {
  __shared__ unsigned short W[73728];   // 144 KB
  __shared__ float LG[8][256];
  __shared__ float rvv[8][16];
  __shared__ int rii[8][16];
  int tid = threadIdx.x, lane = tid & 63, wv = tid >> 6;
  int m15 = lane & 15, lq = lane >> 4, hk8 = lq * 8;
  int blk = blockIdx.x;
  int grp = blk >> 5;
  int gix = blk & 31;
  int j8 = gix * 8;
  int KT = (grp == 0) ? 768 : 512;
  int* arr0 = bar;            // cell0 done
  int* arr1 = bar + 1024;     // cell1 done
  int* arr2 = bar + 2048;     // cell2 done
  int* arr3 = bar + 3072;     // proj done

  {
    int KC = KT >> 3;
    int nvec = 6 * 16 * KC;
    for (int v = tid; v < nvec; v += 512) {
      int c = v % KC;
      int r = (v / KC) & 15;
      int pp = v / (KC * 16);
      int pl = pp >> 1, p = pp & 1;
      int g = (2 * p + (r >> 3)) * 256 + j8 + (r & 7);
      int k = c * 8;
      size_t so;
      if (grp == 0)
        so = (k < 512) ? (size_t)OD0 + (size_t)g * 512 + k
                       : (size_t)ODH + (size_t)g * 256 + (k - 512);
      else if (grp == 1)
        so = (k < 256) ? (size_t)ODR + (size_t)g * 256 + k
                       : (size_t)ODH + 262144 + (size_t)g * 256 + (k - 256);
      else
        so = (k < 256) ? (size_t)ODR + 262144 + (size_t)g * 256 + k
                       : (size_t)ODH + 524288 + (size_t)g * 256 + (k - 256);
      const unsigned short* qs = (pl == 0) ? q0 : ((pl == 1) ? q1 : q2);
      int cs = c ^ (r & 7);
      *(u16x8*)&W[((size_t)pp * 16 + r) * KT + (size_t)cs * 8] = *(const u16x8*)&qs[so];
    }
  }
  __syncthreads();

  int cc8 = m15 & 7;
  int jcol = j8 + cc8;
  float bI = db[grp * 1024 + jcol];
  float bF = db[grp * 1024 + 256 + jcol];
  float bG = db[grp * 1024 + 512 + jcol];
  float bO = db[grp * 1024 + 768 + jcol];
  f32x4 cx[2];
  cx[0] = (f32x4){0.f, 0.f, 0.f, 0.f};
  cx[1] = (f32x4){0.f, 0.f, 0.f, 0.f};

  int gb = gix * 8;
  int mrow = m15 & 7;
  int r0q = lq * 4;
  bool act = (r0q < 8);

  for (int t = 0; t < LDEC; ++t) {
    int pw = (t & 1) ^ 1, pr = t & 1;
    if (grp == 0) { DWAITA(arr3, t) }
    else if (grp == 1) { DWAITA(arr0, t + 1) }
    else { DWAITA(arr1, t + 1) }

    f32x4 acc[2][2];
#pragma unroll
    for (int mt = 0; mt < 2; ++mt)
#pragma unroll
      for (int p = 0; p < 2; ++p) acc[mt][p] = (f32x4){0.f, 0.f, 0.f, 0.f};

    if (grp == 0) {
      if (t == 0) {
        for (int kk = 0; kk < 16; ++kk) {
#pragma unroll
          for (int mt = 0; mt < 2; ++mt) {
            int browA = wv * 32 + mt * 16 + m15;
            const float* src = dec_in0 + (size_t)browA * 512 + kk * 32 + hk8;
            s16x8 a0, a1, a2;
#pragma unroll
            for (int e = 0; e < 8; ++e) {
              float v = src[e];
              unsigned short t0 = bf_hi(v);
              float r1 = v - bf_f(t0);
              unsigned short t1 = bf_hi(r1);
              a0[e] = (short)t0; a1[e] = (short)t1; a2[e] = (short)bf_hi(r1 - bf_f(t1));
            }
            CMM(mt, kk * 4 + lq)
          }
        }
      } else {
        for (int kk = 0; kk < 8; ++kk) {
#pragma unroll
          for (int mt = 0; mt < 2; ++mt) {
            int browA = wv * 32 + mt * 16 + m15;
            int tok = toksG[browA];
            size_t eo = (size_t)OEM + (size_t)tok * 256 + kk * 32 + hk8;
            s16x8 a0 = *(const s16x8*)&q0[eo];
            s16x8 a1 = *(const s16x8*)&q1[eo];
            s16x8 a2 = *(const s16x8*)&q2[eo];
            CMM(mt, kk * 4 + lq)
          }
        }
      }
    } else {
      const unsigned short* x0p = Dh + (size_t)(((grp - 1) * 2 + pw) * 3 + 0) * 65536;
      const unsigned short* x1p = Dh + (size_t)(((grp - 1) * 2 + pw) * 3 + 1) * 65536;
      const unsigned short* x2p = Dh + (size_t)(((grp - 1) * 2 + pw) * 3 + 2) * 65536;
      for (int kk = 0; kk < 8; ++kk) {
#pragma unroll
        for (int mt = 0; mt < 2; ++mt) {
          size_t ao = (size_t)(wv * 32 + mt * 16 + m15) * 256 + kk * 32 + hk8;
          s16x8 a0 = *(const s16x8*)&x0p[ao];
          s16x8 a1 = *(const s16x8*)&x1p[ao];
          s16x8 a2 = *(const s16x8*)&x2p[ao];
          CMM(mt, kk * 4 + lq)
        }
      }
    }
    {
      int cb = (grp == 0) ? 64 : 32;
      const unsigned short* h0p = Dh + (size_t)((grp * 2 + pr) * 3 + 0) * 65536;
      const unsigned short* h1p = Dh + (size_t)((grp * 2 + pr) * 3 + 1) * 65536;
      const unsigned short* h2p = Dh + (size_t)((grp * 2 + pr) * 3 + 2) * 65536;
      for (int kk = 0; kk < 8; ++kk) {
#pragma unroll
        for (int mt = 0; mt < 2; ++mt) {
          size_t ao = (size_t)(wv * 32 + mt * 16 + m15) * 256 + kk * 32 + hk8;
          s16x8 a0 = *(const s16x8*)&h0p[ao];
          s16x8 a1 = *(const s16x8*)&h1p[ao];
          s16x8 a2 = *(const s16x8*)&h2p[ao];
          CMM(mt, cb + kk * 4 + lq)
        }
      }
    }
    {
      unsigned short* hw0 = Dh + (size_t)((grp * 2 + pw) * 3 + 0) * 65536;
      unsigned short* hw1 = Dh + (size_t)((grp * 2 + pw) * 3 + 1) * 65536;
      unsigned short* hw2 = Dh + (size_t)((grp * 2 + pw) * 3 + 2) * 65536;
#pragma unroll
      for (int mt = 0; mt < 2; ++mt) {
        f32x4 fx, ox;
#pragma unroll
        for (int e = 0; e < 4; ++e) {
          fx[e] = __shfl_xor(acc[mt][0][e], 8);
          ox[e] = __shfl_xor(acc[mt][1][e], 8);
        }
        if (m15 < 8) {
#pragma unroll
          for (int r = 0; r < 4; ++r) {
            int brow = wv * 32 + mt * 16 + lq * 4 + r;
            float gi = acc[mt][0][r] + bI;
            float gf = fx[r] + bF;
            float gg = acc[mt][1][r] + bG;
            float go = ox[r] + bO;
            float cn = sigm(gf) * cx[mt][r] + sigm(gi) * tanhf(gg);
            float hn = sigm(go) * tanhf(cn);
            cx[mt][r] = cn;
            unsigned short p0v = bf_hi(hn);
            float rr1 = hn - bf_f(p0v);
            unsigned short p1v = bf_hi(rr1);
            unsigned short p2v = bf_hi(rr1 - bf_f(p1v));
            size_t ho = (size_t)brow * 256 + jcol;
            hw0[ho] = p0v; hw1[ho] = p1v; hw2[ho] = p2v;
          }
        }
      }
    }
    if (grp == 0) { DPOSTA(arr0, t + 1) }
    else if (grp == 1) { DPOSTA(arr1, t + 1) }
    else { DPOSTA(arr2, t + 1) }

    if (grp == 2) {
      DWAITA(arr2, t + 1)
      unsigned short* H2 = &W[49152];
      for (int i = tid; i < 6144; i += 512) {
        int pl = i / 2048;
        int rem = i - pl * 2048;
        int row = rem >> 8, col = rem & 255;
        H2[pl * 2112 + row * 264 + col] =
            Dh[(size_t)((2 * 2 + pw) * 3 + pl) * 65536 + (size_t)(gb + row) * 256 + col];
      }
      __syncthreads();
      f32x4 pacc[2];
#pragma unroll
      for (int jj = 0; jj < 2; ++jj) pacc[jj] = (f32x4){0.f, 0.f, 0.f, 0.f};
      for (int kk = 0; kk < 8; ++kk) {
        s16x8 a0 = *(const s16x8*)&H2[0 * 2112 + mrow * 264 + kk * 32 + hk8];
        s16x8 a1 = *(const s16x8*)&H2[1 * 2112 + mrow * 264 + kk * 32 + hk8];
        s16x8 a2 = *(const s16x8*)&H2[2 * 2112 + mrow * 264 + kk * 32 + hk8];
#pragma unroll
        for (int jj = 0; jj < 2; ++jj) {
          int v = wv * 32 + jj * 16 + m15;
          size_t wo = OPJ + (size_t)v * 256 + kk * 32 + hk8;
          MF6(pacc[jj], q0, q1, q2, wo)
        }
      }
      if (act) {
#pragma unroll
        for (int jj = 0; jj < 2; ++jj) {
          int v = wv * 32 + jj * 16 + m15;
          float pbv = pb[v];
#pragma unroll
          for (int r = 0; r < 4; ++r) LG[r0q + r][v] = pacc[jj][r] + pbv;
        }
      }
      __syncthreads();
      for (int i = tid; i < 2048; i += 512) {
        int row = i >> 8, v = i & 255;
        out[((size_t)(gb + row) * LDEC + t) * 256 + v] = LG[row][v];
      }
      if (tid < 128) {
        int prow = tid >> 4, pp = tid & 15;
        float bv = LG[prow][pp * 16];
        int bidx = pp * 16;
        for (int i2 = 1; i2 < 16; ++i2) {
          float v2 = LG[prow][pp * 16 + i2];
          if (v2 > bv) { bv = v2; bidx = pp * 16 + i2; }
        }
        rvv[prow][pp] = bv;
        rii[prow][pp] = bidx;
      }
      __syncthreads();
      if (tid < 8) {
        float best = rvv[tid][0];
        int bi = rii[tid][0];
        for (int qq = 1; qq < 16; ++qq) {
          float v2 = rvv[tid][qq];
          int ii = rii[tid][qq];
          if (v2 > best || (v2 == best && ii < bi)) { best = v2; bi = ii; }
        }
        toksG[gb + tid] = bi;
      }
      DPOSTA(arr3, t + 1)
    }
  }
}

extern "C" void kernel_launch(void* const* d_in, const int* in_sizes, int n_in,
                              void* d_out, int out_size, void* d_ws, size_t ws_size,
                              hipStream_t stream) {
  const int* text = (const int*)d_in[0];
  const float* emb = (const float*)d_in[2];
  const float* w_ih_l0 = (const float*)d_in[3];
  const float* w_hh_l0 = (const float*)d_in[4];
  const float* b_l0 = (const float*)d_in[5];
  const float* w_ih_r = (const float*)d_in[6];
  const float* w_hh_r = (const float*)d_in[7];
  const float* b_r = (const float*)d_in[8];
  const float* dwih0 = (const float*)d_in[9];
  const float* dwihr = (const float*)d_in[10];
  const float* dwhh = (const float*)d_in[11];
  const float* db = (const float*)d_in[12];
  const float* pw = (const float*)d_in[13];
  const float* pb = (const float*)d_in[14];

  char* ws = (char*)d_ws;
  short *X, *Sf, *Sr;
  unsigned short *wihh, *wihl, *whp0, *whp1, *whp2, *embh, *embl, *Hg, *Dh;
  unsigned short *q0, *q1, *q2;
  float *XG, *Cst, *dec_in;
  int *bar, *toksG;
  int W = 0;
  for (int Wv = 8; Wv >= 4 && W == 0; Wv >>= 1) {
    size_t off = 0;
    X    = (short*)(ws + off);          off += (size_t)Bsz * TN * 512 * 2;
    Sf   = (short*)(ws + off);          off += (size_t)256 * Bsz * 256 * 2;
    Sr   = (short*)(ws + off);          off += (size_t)256 * Bsz * 256 * 2;
    XG   = (float*)(ws + off);          off += (size_t)2 * Wv * 262144 * 4;
    wihh = (unsigned short*)(ws + off); off += 2621440ull * 2;
    wihl = (unsigned short*)(ws + off); off += 2621440ull * 2;
    whp0 = (unsigned short*)(ws + off); off += 1572864ull * 2;
    whp1 = (unsigned short*)(ws + off); off += 1572864ull * 2;
    whp2 = (unsigned short*)(ws + off); off += 1572864ull * 2;
    embh = (unsigned short*)(ws + off); off += 65536 * 2;
    embl = (unsigned short*)(ws + off); off += 65536 * 2;
    q0   = (unsigned short*)(ws + off); off += 1966080ull * 2;
    q1   = (unsigned short*)(ws + off); off += 1966080ull * 2;
    q2   = (unsigned short*)(ws + off); off += 1966080ull * 2;
    Hg   = (unsigned short*)(ws + off); off += 786432ull * 2;
    Dh   = (unsigned short*)(ws + off); off += 1179648ull * 2;
    Cst  = (float*)(ws + off);          off += (size_t)2 * Bsz * Hh * 4;
    dec_in = (float*)(ws + off);        off += (size_t)Bsz * 512 * 4;
    toksG = (int*)(ws + off);           off += 1024;
    bar  = (int*)(ws + off);            off += 40960;   // 3*2048 enc + 4096 dec slots
    if (ws_size >= off) W = Wv;
  }
  if (W == 0) {
    float dval = 1000.0f + (float)(ws_size >> 20);
    k_fill<<<(out_size + 255) / 256, 256, 0, stream>>>((float*)d_out, out_size, dval);
    return;
  }

  // zero all barrier slots (graph-replay safe)
  k_fill<<<40, 256, 0, stream>>>((float*)bar, 10240, 0.f);
  // zero decoder h-state (both parities)
  k_fill<<<2304, 256, 0, stream>>>((float*)Dh, 589824, 0.f);

  k_split<<<2048, 256, 0, stream>>>(w_ih_l0, wihh, wihl, 524288);
  k_split<<<8192, 256, 0, stream>>>(w_ih_r, wihh + 524288, wihl + 524288, 2097152);
  k_split<<<256, 256, 0, stream>>>(emb, embh, embl, 65536);
  k_split3<<<2048, 256, 0, stream>>>(w_hh_l0, whp0, whp1, whp2, 524288);
  k_split3<<<4096, 256, 0, stream>>>(w_hh_r, whp0 + 524288, whp1 + 524288, whp2 + 524288, 1048576);
  k_split3<<<2048, 256, 0, stream>>>(dwih0, q0 + OD0, q1 + OD0, q2 + OD0, 524288);
  k_split3<<<2048, 256, 0, stream>>>(dwihr, q0 + ODR, q1 + ODR, q2 + ODR, 524288);
  k_split3<<<3072, 256, 0, stream>>>(dwhh, q0 + ODH, q1 + ODH, q2 + ODH, 786432);
  k_split3<<<256, 256, 0, stream>>>(pw, q0 + OPJ, q1 + OPJ, q2 + OPJ, 65536);
  k_split3<<<256, 256, 0, stream>>>(emb, q0 + OEM, q1 + OEM, q2 + OEM, 65536);

  for (int l = 0; l < 3; ++l) {
    int K = (l == 0) ? 256 : 512;
    const unsigned short *wih_h, *wih_l;
    int wstride;
    const float* bias;
    if (l == 0) {
      wih_h = wihh; wih_l = wihl; wstride = 262144;
      bias = b_l0;
    } else {
      size_t wo = 524288 + (size_t)(l - 1) * 1048576;
      wih_h = wihh + wo; wih_l = wihl + wo; wstride = 524288;
      bias = b_r + (size_t)(l - 1) * 2048;
    }
    size_t wl_off = (size_t)((l == 0) ? 0 : 2 * l) * 262144;
    int mode = (l == 2) ? 2 : ((l == 1) ? 1 : 0);
    k_fill<<<1536, 256, 0, stream>>>((float*)Hg, 393216, 0.f);
    int nwin = TN / W;
    for (int ch = 0; ch < nwin; ++ch) {
      int s0 = ch * W;
      int both = !(l == 2 && ch > 0);
      int Z = both ? 2 * W : W;
      k_gemm<<<dim3(4, 8, Z), 256, 0, stream>>>(X, text, embh, embl, (l == 0) ? 1 : 0, K,
                                                wih_h, wih_l, wstride, bias, XG, s0, both);
      k_wstep<<<dim3(16, 2, 2), 512, 0, stream>>>(XG, whp0 + wl_off, whp1 + wl_off,
                                                  whp2 + wl_off, Hg, Cst,
                                                  X, Sf, Sr, dec_in, bar + l * 2048, s0, W, mode);
    }
    if (l == 1) k_flush<<<dim3(8192, 2), 256, 0, stream>>>(X, Sf, Sr);
  }

  k_dec2<<<96, 512, 0, stream>>>(dec_in, q0, q1, q2, db, pb, Dh, toksG,
                                 bar + 6144, (float*)d_out);
}